// Round 2
// baseline (690.532 us; speedup 1.0000x reference)
//
#include <hip/hip_runtime.h>
#include <hip/hip_bf16.h>

#define N_NODES 10000
#define N_EDGES 320000
#define D 128
#define H 512

typedef __bf16 bf16x8 __attribute__((ext_vector_type(8)));
typedef float f32x4 __attribute__((ext_vector_type(4)));
typedef unsigned short u16x8 __attribute__((ext_vector_type(8)));

__device__ __forceinline__ unsigned short f2bf(float f) {
    union { float f; unsigned u; } v; v.f = f;
    unsigned r = v.u + 0x7fffu + ((v.u >> 16) & 1u);
    return (unsigned short)(r >> 16);
}

// ---------------- precompute: cast x to bf16 ----------------
__global__ void cast_x_kernel(const float* __restrict__ x, unsigned short* __restrict__ xb) {
    int t = blockIdx.x * 256 + threadIdx.x;        // exactly N_NODES*D/4 threads
    float4 v = reinterpret_cast<const float4*>(x)[t];
    ushort4 o;
    o.x = f2bf(v.x); o.y = f2bf(v.y); o.z = f2bf(v.z); o.w = f2bf(v.w);
    reinterpret_cast<ushort4*>(xb)[t] = o;
}

// ---------------- precompute: swizzle weight [K][N] fp32 -> MFMA-B-frag layout bf16 ----
__global__ void swizzle_w_kernel(const float* __restrict__ W, unsigned short* __restrict__ out,
                                 int K, int Nn) {
    int t = blockIdx.x * 256 + threadIdx.x;
    int total = (K >> 5) * (Nn >> 4) * 64;
    if (t >= total) return;
    int lane = t & 63;
    int tile = t >> 6;
    int ntiles = Nn >> 4;
    int nt = tile % ntiles;
    int kt = tile / ntiles;
    int k0 = kt * 32 + (lane >> 4) * 8;
    int n  = nt * 16 + (lane & 15);
    unsigned short tmp[8];
#pragma unroll
    for (int j = 0; j < 8; ++j) tmp[j] = f2bf(W[(size_t)(k0 + j) * Nn + n]);
    ushort4* dst = reinterpret_cast<ushort4*>(out + (size_t)t * 8);
    dst[0] = *reinterpret_cast<ushort4*>(&tmp[0]);
    dst[1] = *reinterpret_cast<ushort4*>(&tmp[4]);
}

// ---------------- CSR build: histogram -> scan -> scatter ----------------
__global__ void hist_kernel(const int* __restrict__ eidx, int* __restrict__ deg) {
    int e = blockIdx.x * 256 + threadIdx.x;
    if (e < N_EDGES) atomicAdd(&deg[eidx[N_EDGES + e]], 1);
}

__global__ __launch_bounds__(1024) void scan_kernel(const int* __restrict__ deg,
                                                    int* __restrict__ rowstart,
                                                    int* __restrict__ cursor) {
    __shared__ int wsums[16];
    const int t = threadIdx.x;              // 1024 threads, 10 nodes each
    const int lane = t & 63, wv = t >> 6;
    const int base = t * 10;
    int loc[10];
    int s = 0;
#pragma unroll
    for (int i = 0; i < 10; ++i) {
        int v = (base + i < N_NODES) ? deg[base + i] : 0;
        loc[i] = s; s += v;
    }
    const int tot = s;
    int inc = tot;
#pragma unroll
    for (int d = 1; d < 64; d <<= 1) {
        int n = __shfl_up(inc, d, 64);
        if (lane >= d) inc += n;
    }
    if (lane == 63) wsums[wv] = inc;
    __syncthreads();
    if (t == 0) {
        int run = 0;
#pragma unroll
        for (int w = 0; w < 16; ++w) { int v = wsums[w]; wsums[w] = run; run += v; }
    }
    __syncthreads();
    const int off = wsums[wv] + inc - tot;
#pragma unroll
    for (int i = 0; i < 10; ++i) {
        int idx = base + i;
        if (idx < N_NODES) { int v = off + loc[i]; rowstart[idx] = v; cursor[idx] = v; }
    }
    if (t == 1023) rowstart[N_NODES] = off + tot;
}

__global__ void scatter_kernel(const int* __restrict__ eidx, int* __restrict__ cursor,
                               int* __restrict__ elist) {
    int e = blockIdx.x * 256 + threadIdx.x;
    if (e < N_EDGES) {
        int p = atomicAdd(&cursor[eidx[N_EDGES + e]], 1);
        elist[p] = e;
    }
}

// ---------------- aggregation: one wave per node, CSR order ----------------
// lane owns 2 cols (float2 = 8B). Per edge: 64 lanes read one contiguous 512B row.
__global__ __launch_bounds__(256) void agg_kernel(
    const float* __restrict__ out_edges,
    const int* __restrict__ rowstart,
    const int* __restrict__ elist,
    unsigned short* __restrict__ aggb)      // [N_NODES][128] bf16
{
    int node = blockIdx.x * 4 + (threadIdx.x >> 6);
    int lane = threadIdx.x & 63;
    int r0 = rowstart[node], r1 = rowstart[node + 1];
    float sx = 0.f, sy = 0.f;
    for (int j = r0; j < r1; ++j) {
        int e = elist[j];                    // wave-uniform -> scalar load
        float2 v = *reinterpret_cast<const float2*>(&out_edges[(size_t)e * 128 + lane * 2]);
        sx += v.x; sy += v.y;
    }
    ushort2 o; o.x = f2bf(sx); o.y = f2bf(sy);
    *reinterpret_cast<ushort2*>(&aggb[(size_t)node * 128 + lane * 2]) = o;
}

// ---------------- fused edge MLP (stores only, sH ping-pong aliased in sA) ----------------
__global__ __launch_bounds__(256, 2) void edge_mlp_kernel(
    const unsigned short* __restrict__ xb,
    const int* __restrict__ eidx,
    const float* __restrict__ edge_attr,
    const unsigned short* __restrict__ We1s,
    const float* __restrict__ be1,
    const unsigned short* __restrict__ We2s,
    const float* __restrict__ be2,
    float* __restrict__ out_edges)
{
    __shared__ unsigned short sA[64 * 392];   // [64][384+8] bf16; reused as 2x sH after GEMM1
    unsigned short* const sH0 = sA;           // [64][136]
    unsigned short* const sH1 = sA + 64 * 136;

    const int tid = threadIdx.x;
    const int wave = tid >> 6, lane = tid & 63;
    const int e0 = blockIdx.x * 64;
    const int l15 = lane & 15;
    const int q8 = (lane >> 4) * 8;

    // ---- stage A: concat(x[s], x[r], edge_attr) as bf16 ----
#pragma unroll
    for (int seg = 0; seg < 2; ++seg) {
        for (int c = tid; c < 1024; c += 256) {
            int row = c >> 4;
            int off = (c & 15) << 3;
            int e = e0 + row;
            int node = eidx[seg * N_EDGES + e];
            *reinterpret_cast<bf16x8*>(&sA[row * 392 + seg * 128 + off]) =
                *reinterpret_cast<const bf16x8*>(&xb[(size_t)node * 128 + off]);
        }
    }
    for (int c = tid; c < 1024; c += 256) {
        int row = c >> 4;
        int off = (c & 15) << 3;
        int e = e0 + row;
        const float4* src = reinterpret_cast<const float4*>(&edge_attr[(size_t)e * 128 + off]);
        float4 v0 = src[0], v1 = src[1];
        u16x8 o;
        o[0] = f2bf(v0.x); o[1] = f2bf(v0.y); o[2] = f2bf(v0.z); o[3] = f2bf(v0.w);
        o[4] = f2bf(v1.x); o[5] = f2bf(v1.y); o[6] = f2bf(v1.z); o[7] = f2bf(v1.w);
        *reinterpret_cast<u16x8*>(&sA[row * 392 + 256 + off]) = o;
    }
    __syncthreads();

    f32x4 acc1[8][4];
#pragma unroll
    for (int j = 0; j < 8; ++j)
#pragma unroll
        for (int mt = 0; mt < 4; ++mt) acc1[j][mt] = (f32x4){0.f, 0.f, 0.f, 0.f};
    f32x4 acc2[2][4];
#pragma unroll
    for (int nn = 0; nn < 2; ++nn)
#pragma unroll
        for (int mt = 0; mt < 4; ++mt) acc2[nn][mt] = (f32x4){0.f, 0.f, 0.f, 0.f};

    // ---- GEMM1: one pass over K=384, wave owns 8 n-tiles ----
#pragma unroll 2
    for (int kt = 0; kt < 12; ++kt) {
        bf16x8 a[4];
#pragma unroll
        for (int mt = 0; mt < 4; ++mt)
            a[mt] = *reinterpret_cast<const bf16x8*>(&sA[(mt * 16 + l15) * 392 + kt * 32 + q8]);
#pragma unroll
        for (int j = 0; j < 8; ++j) {
            int ntile = (j >> 1) * 8 + wave * 2 + (j & 1);
            bf16x8 b = *reinterpret_cast<const bf16x8*>(
                &We1s[(((size_t)kt * 32 + ntile) * 64 + lane) * 8]);
#pragma unroll
            for (int mt = 0; mt < 4; ++mt)
                acc1[j][mt] = __builtin_amdgcn_mfma_f32_16x16x32_bf16(a[mt], b, acc1[j][mt], 0, 0, 0);
        }
    }

#define WRITE_H(hh, dst, B1)                                                  \
    {                                                                         \
        _Pragma("unroll")                                                     \
        for (int nn = 0; nn < 2; ++nn) {                                      \
            int cc = (wave * 2 + nn) * 16 + l15;                              \
            float bias = (B1)[(hh) * 128 + cc];                               \
            _Pragma("unroll")                                                 \
            for (int mt = 0; mt < 4; ++mt)                                    \
                _Pragma("unroll")                                             \
                for (int r = 0; r < 4; ++r) {                                 \
                    float v = acc1[(hh) * 2 + nn][mt][r] + bias;              \
                    v = v > 0.f ? v : 0.f;                                    \
                    int row = mt * 16 + (lane >> 4) * 4 + r;                  \
                    (dst)[row * 136 + cc] = f2bf(v);                          \
                }                                                             \
        }                                                                     \
    }

#define GEMM2_CHUNK(hh, src, W2)                                              \
    {                                                                         \
        _Pragma("unroll")                                                     \
        for (int kt = 0; kt < 4; ++kt) {                                      \
            bf16x8 a[4];                                                      \
            _Pragma("unroll")                                                 \
            for (int mt = 0; mt < 4; ++mt)                                    \
                a[mt] = *reinterpret_cast<const bf16x8*>(                     \
                    &(src)[(mt * 16 + l15) * 136 + kt * 32 + q8]);            \
            _Pragma("unroll")                                                 \
            for (int nn = 0; nn < 2; ++nn) {                                  \
                int ntile = wave * 2 + nn;                                    \
                bf16x8 b = *reinterpret_cast<const bf16x8*>(                  \
                    &(W2)[(((size_t)((hh) * 4 + kt) * 8 + ntile) * 64 + lane) * 8]); \
                _Pragma("unroll")                                             \
                for (int mt = 0; mt < 4; ++mt)                                \
                    acc2[nn][mt] = __builtin_amdgcn_mfma_f32_16x16x32_bf16(   \
                        a[mt], b, acc2[nn][mt], 0, 0, 0);                     \
            }                                                                 \
        }                                                                     \
    }

    __syncthreads();                       // all waves done reading sA
    WRITE_H(0, sH0, be1);
    __syncthreads();                       // sH0 visible
#pragma unroll
    for (int h = 0; h < 4; ++h) {
        unsigned short* const cur = (h & 1) ? sH1 : sH0;
        unsigned short* const nxt = (h & 1) ? sH0 : sH1;
        if (h < 3) WRITE_H(h + 1, nxt, be1);   // overlaps GEMM2 below (different buffer)
        GEMM2_CHUNK(h, cur, We2s);
        if (h < 3) __syncthreads();
    }

    // ---- epilogue: plain stores ----
#pragma unroll
    for (int nn = 0; nn < 2; ++nn) {
        int cc = (wave * 2 + nn) * 16 + l15;
        float bias = be2[cc];
#pragma unroll
        for (int mt = 0; mt < 4; ++mt)
#pragma unroll
            for (int r = 0; r < 4; ++r) {
                int row = mt * 16 + (lane >> 4) * 4 + r;
                out_edges[(size_t)(e0 + row) * 128 + cc] = acc2[nn][mt][r] + bias;
            }
    }
}

// ---------------- fused node MLP (stages from aggb, sH ping-pong) ----------------
__global__ __launch_bounds__(256, 2) void node_mlp_kernel(
    const unsigned short* __restrict__ xb,
    const unsigned short* __restrict__ aggb,
    const unsigned short* __restrict__ Wn1s,
    const float* __restrict__ bn1,
    const unsigned short* __restrict__ Wn2s,
    const float* __restrict__ bn2,
    float* __restrict__ out_nodes)
{
    __shared__ unsigned short sA[17408];      // stage: [64][256+8]=16896; sH ping-pong: 2x8704
    unsigned short* const sH0 = sA;
    unsigned short* const sH1 = sA + 64 * 136;

    const int tid = threadIdx.x;
    const int wave = tid >> 6, lane = tid & 63;
    const int n0 = blockIdx.x * 64;
    const int l15 = lane & 15;
    const int q8 = (lane >> 4) * 8;

    // stage: concat(x_bf16, agg_bf16)
    for (int c = tid; c < 1024; c += 256) {
        int row = c >> 4;
        int off = (c & 15) << 3;
        int node = n0 + row;
        bf16x8 v = {};
        if (node < N_NODES)
            v = *reinterpret_cast<const bf16x8*>(&xb[(size_t)node * 128 + off]);
        *reinterpret_cast<bf16x8*>(&sA[row * 264 + off]) = v;
    }
    for (int c = tid; c < 1024; c += 256) {
        int row = c >> 4;
        int off = (c & 15) << 3;
        int node = n0 + row;
        bf16x8 v = {};
        if (node < N_NODES)
            v = *reinterpret_cast<const bf16x8*>(&aggb[(size_t)node * 128 + off]);
        *reinterpret_cast<bf16x8*>(&sA[row * 264 + 128 + off]) = v;
    }
    __syncthreads();

    f32x4 acc1[8][4];
#pragma unroll
    for (int j = 0; j < 8; ++j)
#pragma unroll
        for (int mt = 0; mt < 4; ++mt) acc1[j][mt] = (f32x4){0.f, 0.f, 0.f, 0.f};
    f32x4 acc2[2][4];
#pragma unroll
    for (int nn = 0; nn < 2; ++nn)
#pragma unroll
        for (int mt = 0; mt < 4; ++mt) acc2[nn][mt] = (f32x4){0.f, 0.f, 0.f, 0.f};

    // GEMM1 single pass over K=256
#pragma unroll 2
    for (int kt = 0; kt < 8; ++kt) {
        bf16x8 a[4];
#pragma unroll
        for (int mt = 0; mt < 4; ++mt)
            a[mt] = *reinterpret_cast<const bf16x8*>(&sA[(mt * 16 + l15) * 264 + kt * 32 + q8]);
#pragma unroll
        for (int j = 0; j < 8; ++j) {
            int ntile = (j >> 1) * 8 + wave * 2 + (j & 1);
            bf16x8 b = *reinterpret_cast<const bf16x8*>(
                &Wn1s[(((size_t)kt * 32 + ntile) * 64 + lane) * 8]);
#pragma unroll
            for (int mt = 0; mt < 4; ++mt)
                acc1[j][mt] = __builtin_amdgcn_mfma_f32_16x16x32_bf16(a[mt], b, acc1[j][mt], 0, 0, 0);
        }
    }

    __syncthreads();
    WRITE_H(0, sH0, bn1);
    __syncthreads();
#pragma unroll
    for (int h = 0; h < 4; ++h) {
        unsigned short* const cur = (h & 1) ? sH1 : sH0;
        unsigned short* const nxt = (h & 1) ? sH0 : sH1;
        if (h < 3) WRITE_H(h + 1, nxt, bn1);
        GEMM2_CHUNK(h, cur, Wn2s);
        if (h < 3) __syncthreads();
    }

#pragma unroll
    for (int nn = 0; nn < 2; ++nn) {
        int cc = (wave * 2 + nn) * 16 + l15;
        float bias = bn2[cc];
#pragma unroll
        for (int mt = 0; mt < 4; ++mt)
#pragma unroll
            for (int r = 0; r < 4; ++r) {
                int row = mt * 16 + (lane >> 4) * 4 + r;
                int node = n0 + row;
                if (node < N_NODES)
                    out_nodes[(size_t)node * 128 + cc] = acc2[nn][mt][r] + bias;
            }
    }
}

extern "C" void kernel_launch(void* const* d_in, const int* in_sizes, int n_in,
                              void* d_out, int out_size, void* d_ws, size_t ws_size,
                              hipStream_t stream) {
    const float* x         = (const float*)d_in[0];
    const int*   eidx      = (const int*)d_in[1];
    const float* edge_attr = (const float*)d_in[2];
    const float* We1       = (const float*)d_in[3];
    const float* be1       = (const float*)d_in[4];
    const float* We2       = (const float*)d_in[5];
    const float* be2       = (const float*)d_in[6];
    const float* Wn1       = (const float*)d_in[7];
    const float* bn1       = (const float*)d_in[8];
    const float* Wn2       = (const float*)d_in[9];
    const float* bn2       = (const float*)d_in[10];
    float* out = (float*)d_out;

    char* ws = (char*)d_ws;
    size_t off = 0;
    auto alloc = [&](size_t bytes) {
        void* p = ws + off;
        off += (bytes + 255) & ~(size_t)255;
        return p;
    };
    unsigned short* xb   = (unsigned short*)alloc((size_t)N_NODES * D * 2);
    unsigned short* We1s = (unsigned short*)alloc((size_t)384 * 512 * 2);
    unsigned short* We2s = (unsigned short*)alloc((size_t)512 * 128 * 2);
    unsigned short* Wn1s = (unsigned short*)alloc((size_t)256 * 512 * 2);
    unsigned short* Wn2s = (unsigned short*)alloc((size_t)512 * 128 * 2);
    unsigned short* aggb = (unsigned short*)alloc((size_t)N_NODES * D * 2);
    int* deg      = (int*)alloc((size_t)(N_NODES + 1) * 4);
    int* rowstart = (int*)alloc((size_t)(N_NODES + 1) * 4);
    int* cursor   = (int*)alloc((size_t)(N_NODES + 1) * 4);
    int* elist    = (int*)alloc((size_t)N_EDGES * 4);

    float* out_edges = out + (size_t)N_NODES * D;

    hipMemsetAsync(deg, 0, (size_t)N_NODES * sizeof(int), stream);
    cast_x_kernel<<<(N_NODES * D / 4 + 255) / 256, 256, 0, stream>>>(x, xb);
    swizzle_w_kernel<<<(12 * 32 * 64 + 255) / 256, 256, 0, stream>>>(We1, We1s, 384, 512);
    swizzle_w_kernel<<<(16 * 8 * 64 + 255) / 256, 256, 0, stream>>>(We2, We2s, 512, 128);
    swizzle_w_kernel<<<(8 * 32 * 64 + 255) / 256, 256, 0, stream>>>(Wn1, Wn1s, 256, 512);
    swizzle_w_kernel<<<(16 * 8 * 64 + 255) / 256, 256, 0, stream>>>(Wn2, Wn2s, 512, 128);

    // CSR build
    hist_kernel<<<(N_EDGES + 255) / 256, 256, 0, stream>>>(eidx, deg);
    scan_kernel<<<1, 1024, 0, stream>>>(deg, rowstart, cursor);
    scatter_kernel<<<(N_EDGES + 255) / 256, 256, 0, stream>>>(eidx, cursor, elist);

    edge_mlp_kernel<<<N_EDGES / 64, 256, 0, stream>>>(
        xb, eidx, edge_attr, We1s, be1, We2s, be2, out_edges);
    agg_kernel<<<N_NODES / 4, 256, 0, stream>>>(out_edges, rowstart, elist, aggb);
    node_mlp_kernel<<<(N_NODES + 63) / 64, 256, 0, stream>>>(
        xb, aggb, Wn1s, bn1, Wn2s, bn2, out);
}

// Round 3
// 611.105 us; speedup vs baseline: 1.1300x; 1.1300x over previous
//
#include <hip/hip_runtime.h>
#include <hip/hip_bf16.h>

#define N_NODES 10000
#define N_EDGES 320000
#define D 128
#define H 512

typedef __bf16 bf16x8 __attribute__((ext_vector_type(8)));
typedef float f32x4 __attribute__((ext_vector_type(4)));
typedef unsigned short u16x8 __attribute__((ext_vector_type(8)));

__device__ __forceinline__ unsigned short f2bf(float f) {
    union { float f; unsigned u; } v; v.f = f;
    unsigned r = v.u + 0x7fffu + ((v.u >> 16) & 1u);
    return (unsigned short)(r >> 16);
}

// ---------------- precompute: cast x to bf16 ----------------
__global__ void cast_x_kernel(const float* __restrict__ x, unsigned short* __restrict__ xb) {
    int t = blockIdx.x * 256 + threadIdx.x;        // exactly N_NODES*D/4 threads
    float4 v = reinterpret_cast<const float4*>(x)[t];
    ushort4 o;
    o.x = f2bf(v.x); o.y = f2bf(v.y); o.z = f2bf(v.z); o.w = f2bf(v.w);
    reinterpret_cast<ushort4*>(xb)[t] = o;
}

// ---------------- precompute: swizzle weight [K][N] fp32 -> MFMA-B-frag layout bf16 ----
__global__ void swizzle_w_kernel(const float* __restrict__ W, unsigned short* __restrict__ out,
                                 int K, int Nn) {
    int t = blockIdx.x * 256 + threadIdx.x;
    int total = (K >> 5) * (Nn >> 4) * 64;
    if (t >= total) return;
    int lane = t & 63;
    int tile = t >> 6;
    int ntiles = Nn >> 4;
    int nt = tile % ntiles;
    int kt = tile / ntiles;
    int k0 = kt * 32 + (lane >> 4) * 8;
    int n  = nt * 16 + (lane & 15);
    unsigned short tmp[8];
#pragma unroll
    for (int j = 0; j < 8; ++j) tmp[j] = f2bf(W[(size_t)(k0 + j) * Nn + n]);
    ushort4* dst = reinterpret_cast<ushort4*>(out + (size_t)t * 8);
    dst[0] = *reinterpret_cast<ushort4*>(&tmp[0]);
    dst[1] = *reinterpret_cast<ushort4*>(&tmp[4]);
}

// ---------------- CSR build: histogram -> scan -> scatter ----------------
__global__ void hist_kernel(const int* __restrict__ eidx, int* __restrict__ deg) {
    int e = blockIdx.x * 256 + threadIdx.x;
    if (e < N_EDGES) atomicAdd(&deg[eidx[N_EDGES + e]], 1);
}

__global__ __launch_bounds__(1024) void scan_kernel(const int* __restrict__ deg,
                                                    int* __restrict__ rowstart,
                                                    int* __restrict__ cursor) {
    __shared__ int wsums[16];
    const int t = threadIdx.x;              // 1024 threads, 10 nodes each
    const int lane = t & 63, wv = t >> 6;
    const int base = t * 10;
    int loc[10];
    int s = 0;
#pragma unroll
    for (int i = 0; i < 10; ++i) {
        int v = (base + i < N_NODES) ? deg[base + i] : 0;
        loc[i] = s; s += v;
    }
    const int tot = s;
    int inc = tot;
#pragma unroll
    for (int d = 1; d < 64; d <<= 1) {
        int n = __shfl_up(inc, d, 64);
        if (lane >= d) inc += n;
    }
    if (lane == 63) wsums[wv] = inc;
    __syncthreads();
    if (t == 0) {
        int run = 0;
#pragma unroll
        for (int w = 0; w < 16; ++w) { int v = wsums[w]; wsums[w] = run; run += v; }
    }
    __syncthreads();
    const int off = wsums[wv] + inc - tot;
#pragma unroll
    for (int i = 0; i < 10; ++i) {
        int idx = base + i;
        if (idx < N_NODES) { int v = off + loc[i]; rowstart[idx] = v; cursor[idx] = v; }
    }
    if (t == 1023) rowstart[N_NODES] = off + tot;
}

__global__ void scatter_kernel(const int* __restrict__ eidx, int* __restrict__ cursor,
                               int* __restrict__ elist) {
    int e = blockIdx.x * 256 + threadIdx.x;
    if (e < N_EDGES) {
        int p = atomicAdd(&cursor[eidx[N_EDGES + e]], 1);
        elist[p] = e;
    }
}

// ---------------- aggregation: one wave per node, CSR order ----------------
__global__ __launch_bounds__(256) void agg_kernel(
    const float* __restrict__ out_edges,
    const int* __restrict__ rowstart,
    const int* __restrict__ elist,
    unsigned short* __restrict__ aggb)      // [N_NODES][128] bf16
{
    int node = blockIdx.x * 4 + (threadIdx.x >> 6);
    int lane = threadIdx.x & 63;
    int r0 = rowstart[node], r1 = rowstart[node + 1];
    float sx = 0.f, sy = 0.f;
    for (int j = r0; j < r1; ++j) {
        int e = elist[j];                    // wave-uniform -> scalar load
        float2 v = *reinterpret_cast<const float2*>(&out_edges[(size_t)e * 128 + lane * 2]);
        sx += v.x; sy += v.y;
    }
    ushort2 o; o.x = f2bf(sx); o.y = f2bf(sy);
    *reinterpret_cast<ushort2*>(&aggb[(size_t)node * 128 + lane * 2]) = o;
}

// ---------------- edge MLP: M=128, 8 waves, LDS-staged A/B via global_load_lds ----------------
// A-slice per kt: [128 rows][32 k-elems] bf16, 8 KB, lane-linear LDS layout with
// XOR-swizzled SOURCE quad (q ^ (row&3)) so ds_read can de-swizzle (rule #21).
// B-slice per kt: 32 KB linear copy of We1s kt-slice (frag layout already).
__device__ __forceinline__ void gld_lds16(const void* g, void* l) {
    __builtin_amdgcn_global_load_lds((const __attribute__((address_space(1))) void*)g,
                                     (__attribute__((address_space(3))) void*)l, 16, 0, 0);
}

__device__ __forceinline__ void stage_a(int kt, unsigned short* Abuf, int wave, int lane,
                                        const unsigned short* aS, const unsigned short* aR,
                                        const float* aE) {
    if (kt < 8) {
        const unsigned short* src = (kt < 4) ? (aS + kt * 32) : (aR + (kt - 4) * 32);
        gld_lds16(src, Abuf + wave * 512);       // HW: dest = base + lane*16B
    } else {
        const float* s = aE + (kt - 8) * 32;
        float4 v0 = *reinterpret_cast<const float4*>(s);
        float4 v1 = *reinterpret_cast<const float4*>(s + 4);
        u16x8 o;
        o[0] = f2bf(v0.x); o[1] = f2bf(v0.y); o[2] = f2bf(v0.z); o[3] = f2bf(v0.w);
        o[4] = f2bf(v1.x); o[5] = f2bf(v1.y); o[6] = f2bf(v1.z); o[7] = f2bf(v1.w);
        *reinterpret_cast<u16x8*>(Abuf + wave * 512 + lane * 8) = o;
    }
}

__device__ __forceinline__ void stage_b(int kt, unsigned short* Bbuf, int wave, int lane,
                                        const unsigned short* We1s) {
#pragma unroll
    for (int i = 0; i < 4; ++i) {
        int c = wave * 4 + i;                    // n-tile chunk 0..31
        const unsigned short* src = We1s + ((size_t)kt * 32 + c) * 512 + lane * 8;
        gld_lds16(src, Bbuf + c * 512);
    }
}

__global__ __launch_bounds__(512, 2) void edge_mlp_kernel(
    const unsigned short* __restrict__ xb,
    const int* __restrict__ eidx,
    const float* __restrict__ edge_attr,
    const unsigned short* __restrict__ We1s,
    const float* __restrict__ be1,
    const unsigned short* __restrict__ We2s,
    const float* __restrict__ be2,
    float* __restrict__ out_edges)
{
    __shared__ unsigned short smem[40960];       // 81920 B
    unsigned short* const A0  = smem;            // 8 KB  (bytes 0..8192)
    unsigned short* const A1  = smem + 4096;     // 8 KB  (8192..16384)
    unsigned short* const B0  = smem + 8192;     // 32 KB (16384..49152)
    unsigned short* const B1  = smem + 24576;    // 32 KB (49152..81920)
    unsigned short* const sH0 = smem + 4096;     // alias after GEMM1 (8192..43008)
    unsigned short* const sH1 = smem + 21504;    // alias (43008..77824)

    const int tid = threadIdx.x;
    const int wave = tid >> 6, lane = tid & 63;
    const int wr = wave >> 2, wc = wave & 3;     // wave-row (M), wave-col (N)
    const int l15 = lane & 15;
    const int Q = lane >> 4;                     // k-quad 0..3
    const int e0 = blockIdx.x * 128;

    // staging constants: this lane stages row rs, swizzled source quad sq
    const int rs = wave * 16 + (lane >> 2);
    const int sq = (lane & 3) ^ (rs & 3);
    const int nS = eidx[e0 + rs];
    const int nR = eidx[N_EDGES + e0 + rs];
    const unsigned short* aS = xb + (size_t)nS * 128 + sq * 8;
    const unsigned short* aR = xb + (size_t)nR * 128 + sq * 8;
    const float*          aE = edge_attr + (size_t)(e0 + rs) * 128 + sq * 8;

    f32x4 acc1[8][4];
#pragma unroll
    for (int j = 0; j < 8; ++j)
#pragma unroll
        for (int mt = 0; mt < 4; ++mt) acc1[j][mt] = (f32x4){0.f, 0.f, 0.f, 0.f};
    f32x4 acc2[2][4];
#pragma unroll
    for (int nn = 0; nn < 2; ++nn)
#pragma unroll
        for (int mt = 0; mt < 4; ++mt) acc2[nn][mt] = (f32x4){0.f, 0.f, 0.f, 0.f};

    // prologue: stage kt=0
    stage_a(0, A0, wave, lane, aS, aR, aE);
    stage_b(0, B0, wave, lane, We1s);
    __syncthreads();

    // ---- GEMM1: K=384, double-buffered LDS staging ----
#pragma unroll
    for (int kt = 0; kt < 12; ++kt) {
        unsigned short* const Ac = (kt & 1) ? A1 : A0;
        unsigned short* const Bc = (kt & 1) ? B1 : B0;
        if (kt < 11) {
            stage_a(kt + 1, (kt & 1) ? A0 : A1, wave, lane, aS, aR, aE);
            stage_b(kt + 1, (kt & 1) ? B0 : B1, wave, lane, We1s);
        }
        bf16x8 a[4];
#pragma unroll
        for (int mt = 0; mt < 4; ++mt) {
            int R = wr * 64 + mt * 16 + l15;
            a[mt] = *reinterpret_cast<const bf16x8*>(&Ac[R * 32 + ((Q ^ (R & 3)) * 8)]);
        }
#pragma unroll
        for (int j = 0; j < 8; ++j) {
            int ntile = (j >> 1) * 8 + wc * 2 + (j & 1);
            bf16x8 b = *reinterpret_cast<const bf16x8*>(&Bc[ntile * 512 + lane * 8]);
#pragma unroll
            for (int mt = 0; mt < 4; ++mt)
                acc1[j][mt] = __builtin_amdgcn_mfma_f32_16x16x32_bf16(a[mt], b, acc1[j][mt], 0, 0, 0);
        }
        __syncthreads();   // drains kt+1 staging; protects dbuf + sH aliasing
    }

    // ---- hidden chunks -> GEMM2 (sH ping-pong aliased over A/B buffers) ----
#define EWRITE_H(hh, dst)                                                     \
    {                                                                         \
        _Pragma("unroll")                                                     \
        for (int nn = 0; nn < 2; ++nn) {                                      \
            int cc = (wc * 2 + nn) * 16 + l15;                                \
            float bias = be1[(hh) * 128 + cc];                                \
            _Pragma("unroll")                                                 \
            for (int mt = 0; mt < 4; ++mt)                                    \
                _Pragma("unroll")                                             \
                for (int r = 0; r < 4; ++r) {                                 \
                    float v = acc1[(hh) * 2 + nn][mt][r] + bias;              \
                    v = v > 0.f ? v : 0.f;                                    \
                    int row = wr * 64 + mt * 16 + (lane >> 4) * 4 + r;        \
                    (dst)[row * 136 + cc] = f2bf(v);                          \
                }                                                             \
        }                                                                     \
    }

    EWRITE_H(0, sH0);
    __syncthreads();
#pragma unroll
    for (int h = 0; h < 4; ++h) {
        unsigned short* const cur = (h & 1) ? sH1 : sH0;
        unsigned short* const nxt = (h & 1) ? sH0 : sH1;
        if (h < 3) EWRITE_H(h + 1, nxt);
#pragma unroll
        for (int kt = 0; kt < 4; ++kt) {
            bf16x8 a[4];
#pragma unroll
            for (int mt = 0; mt < 4; ++mt) {
                int R = wr * 64 + mt * 16 + l15;
                a[mt] = *reinterpret_cast<const bf16x8*>(&cur[R * 136 + kt * 32 + Q * 8]);
            }
#pragma unroll
            for (int nn = 0; nn < 2; ++nn) {
                int ntile = wc * 2 + nn;
                bf16x8 b = *reinterpret_cast<const bf16x8*>(
                    &We2s[(((size_t)(h * 4 + kt) * 8 + ntile) * 64 + lane) * 8]);
#pragma unroll
                for (int mt = 0; mt < 4; ++mt)
                    acc2[nn][mt] = __builtin_amdgcn_mfma_f32_16x16x32_bf16(a[mt], b, acc2[nn][mt], 0, 0, 0);
            }
        }
        if (h < 3) __syncthreads();
    }

    // ---- epilogue: nontemporal stores (don't pollute L2) ----
#pragma unroll
    for (int nn = 0; nn < 2; ++nn) {
        int cc = (wc * 2 + nn) * 16 + l15;
        float bias = be2[cc];
#pragma unroll
        for (int mt = 0; mt < 4; ++mt)
#pragma unroll
            for (int r = 0; r < 4; ++r) {
                int row = wr * 64 + mt * 16 + (lane >> 4) * 4 + r;
                __builtin_nontemporal_store(acc2[nn][mt][r] + bias,
                                            &out_edges[(size_t)(e0 + row) * 128 + cc]);
            }
    }
}

// ---------------- fused node MLP (round-2 structure, unchanged) ----------------
#define WRITE_H(hh, dst, B1)                                                  \
    {                                                                         \
        _Pragma("unroll")                                                     \
        for (int nn = 0; nn < 2; ++nn) {                                      \
            int cc = (wave * 2 + nn) * 16 + l15;                              \
            float bias = (B1)[(hh) * 128 + cc];                               \
            _Pragma("unroll")                                                 \
            for (int mt = 0; mt < 4; ++mt)                                    \
                _Pragma("unroll")                                             \
                for (int r = 0; r < 4; ++r) {                                 \
                    float v = acc1[(hh) * 2 + nn][mt][r] + bias;              \
                    v = v > 0.f ? v : 0.f;                                    \
                    int row = mt * 16 + (lane >> 4) * 4 + r;                  \
                    (dst)[row * 136 + cc] = f2bf(v);                          \
                }                                                             \
        }                                                                     \
    }

#define GEMM2_CHUNK(hh, src, W2)                                              \
    {                                                                         \
        _Pragma("unroll")                                                     \
        for (int kt = 0; kt < 4; ++kt) {                                      \
            bf16x8 a[4];                                                      \
            _Pragma("unroll")                                                 \
            for (int mt = 0; mt < 4; ++mt)                                    \
                a[mt] = *reinterpret_cast<const bf16x8*>(                     \
                    &(src)[(mt * 16 + l15) * 136 + kt * 32 + q8]);            \
            _Pragma("unroll")                                                 \
            for (int nn = 0; nn < 2; ++nn) {                                  \
                int ntile = wave * 2 + nn;                                    \
                bf16x8 b = *reinterpret_cast<const bf16x8*>(                  \
                    &(W2)[(((size_t)((hh) * 4 + kt) * 8 + ntile) * 64 + lane) * 8]); \
                _Pragma("unroll")                                             \
                for (int mt = 0; mt < 4; ++mt)                                \
                    acc2[nn][mt] = __builtin_amdgcn_mfma_f32_16x16x32_bf16(   \
                        a[mt], b, acc2[nn][mt], 0, 0, 0);                     \
            }                                                                 \
        }                                                                     \
    }

__global__ __launch_bounds__(256, 2) void node_mlp_kernel(
    const unsigned short* __restrict__ xb,
    const unsigned short* __restrict__ aggb,
    const unsigned short* __restrict__ Wn1s,
    const float* __restrict__ bn1,
    const unsigned short* __restrict__ Wn2s,
    const float* __restrict__ bn2,
    float* __restrict__ out_nodes)
{
    __shared__ unsigned short sA[17408];      // stage [64][264]; sH ping-pong aliased
    unsigned short* const sH0 = sA;
    unsigned short* const sH1 = sA + 64 * 136;

    const int tid = threadIdx.x;
    const int wave = tid >> 6, lane = tid & 63;
    const int n0 = blockIdx.x * 64;
    const int l15 = lane & 15;
    const int q8 = (lane >> 4) * 8;

    for (int c = tid; c < 1024; c += 256) {
        int row = c >> 4;
        int off = (c & 15) << 3;
        int node = n0 + row;
        bf16x8 v = {};
        if (node < N_NODES)
            v = *reinterpret_cast<const bf16x8*>(&xb[(size_t)node * 128 + off]);
        *reinterpret_cast<bf16x8*>(&sA[row * 264 + off]) = v;
    }
    for (int c = tid; c < 1024; c += 256) {
        int row = c >> 4;
        int off = (c & 15) << 3;
        int node = n0 + row;
        bf16x8 v = {};
        if (node < N_NODES)
            v = *reinterpret_cast<const bf16x8*>(&aggb[(size_t)node * 128 + off]);
        *reinterpret_cast<bf16x8*>(&sA[row * 264 + 128 + off]) = v;
    }
    __syncthreads();

    f32x4 acc1[8][4];
#pragma unroll
    for (int j = 0; j < 8; ++j)
#pragma unroll
        for (int mt = 0; mt < 4; ++mt) acc1[j][mt] = (f32x4){0.f, 0.f, 0.f, 0.f};
    f32x4 acc2[2][4];
#pragma unroll
    for (int nn = 0; nn < 2; ++nn)
#pragma unroll
        for (int mt = 0; mt < 4; ++mt) acc2[nn][mt] = (f32x4){0.f, 0.f, 0.f, 0.f};

#pragma unroll 2
    for (int kt = 0; kt < 8; ++kt) {
        bf16x8 a[4];
#pragma unroll
        for (int mt = 0; mt < 4; ++mt)
            a[mt] = *reinterpret_cast<const bf16x8*>(&sA[(mt * 16 + l15) * 264 + kt * 32 + q8]);
#pragma unroll
        for (int j = 0; j < 8; ++j) {
            int ntile = (j >> 1) * 8 + wave * 2 + (j & 1);
            bf16x8 b = *reinterpret_cast<const bf16x8*>(
                &Wn1s[(((size_t)kt * 32 + ntile) * 64 + lane) * 8]);
#pragma unroll
            for (int mt = 0; mt < 4; ++mt)
                acc1[j][mt] = __builtin_amdgcn_mfma_f32_16x16x32_bf16(a[mt], b, acc1[j][mt], 0, 0, 0);
        }
    }

    __syncthreads();
    WRITE_H(0, sH0, bn1);
    __syncthreads();
#pragma unroll
    for (int h = 0; h < 4; ++h) {
        unsigned short* const cur = (h & 1) ? sH1 : sH0;
        unsigned short* const nxt = (h & 1) ? sH0 : sH1;
        if (h < 3) WRITE_H(h + 1, nxt, bn1);
        GEMM2_CHUNK(h, cur, Wn2s);
        if (h < 3) __syncthreads();
    }

#pragma unroll
    for (int nn = 0; nn < 2; ++nn) {
        int cc = (wave * 2 + nn) * 16 + l15;
        float bias = bn2[cc];
#pragma unroll
        for (int mt = 0; mt < 4; ++mt)
#pragma unroll
            for (int r = 0; r < 4; ++r) {
                int row = mt * 16 + (lane >> 4) * 4 + r;
                int node = n0 + row;
                if (node < N_NODES)
                    out_nodes[(size_t)node * 128 + cc] = acc2[nn][mt][r] + bias;
            }
    }
}

extern "C" void kernel_launch(void* const* d_in, const int* in_sizes, int n_in,
                              void* d_out, int out_size, void* d_ws, size_t ws_size,
                              hipStream_t stream) {
    const float* x         = (const float*)d_in[0];
    const int*   eidx      = (const int*)d_in[1];
    const float* edge_attr = (const float*)d_in[2];
    const float* We1       = (const float*)d_in[3];
    const float* be1       = (const float*)d_in[4];
    const float* We2       = (const float*)d_in[5];
    const float* be2       = (const float*)d_in[6];
    const float* Wn1       = (const float*)d_in[7];
    const float* bn1       = (const float*)d_in[8];
    const float* Wn2       = (const float*)d_in[9];
    const float* bn2       = (const float*)d_in[10];
    float* out = (float*)d_out;

    char* ws = (char*)d_ws;
    size_t off = 0;
    auto alloc = [&](size_t bytes) {
        void* p = ws + off;
        off += (bytes + 255) & ~(size_t)255;
        return p;
    };
    unsigned short* xb   = (unsigned short*)alloc((size_t)N_NODES * D * 2);
    unsigned short* We1s = (unsigned short*)alloc((size_t)384 * 512 * 2);
    unsigned short* We2s = (unsigned short*)alloc((size_t)512 * 128 * 2);
    unsigned short* Wn1s = (unsigned short*)alloc((size_t)256 * 512 * 2);
    unsigned short* Wn2s = (unsigned short*)alloc((size_t)512 * 128 * 2);
    unsigned short* aggb = (unsigned short*)alloc((size_t)N_NODES * D * 2);
    int* deg      = (int*)alloc((size_t)(N_NODES + 1) * 4);
    int* rowstart = (int*)alloc((size_t)(N_NODES + 1) * 4);
    int* cursor   = (int*)alloc((size_t)(N_NODES + 1) * 4);
    int* elist    = (int*)alloc((size_t)N_EDGES * 4);

    float* out_edges = out + (size_t)N_NODES * D;

    hipMemsetAsync(deg, 0, (size_t)N_NODES * sizeof(int), stream);
    cast_x_kernel<<<(N_NODES * D / 4 + 255) / 256, 256, 0, stream>>>(x, xb);
    swizzle_w_kernel<<<(12 * 32 * 64 + 255) / 256, 256, 0, stream>>>(We1, We1s, 384, 512);
    swizzle_w_kernel<<<(16 * 8 * 64 + 255) / 256, 256, 0, stream>>>(We2, We2s, 512, 128);
    swizzle_w_kernel<<<(8 * 32 * 64 + 255) / 256, 256, 0, stream>>>(Wn1, Wn1s, 256, 512);
    swizzle_w_kernel<<<(16 * 8 * 64 + 255) / 256, 256, 0, stream>>>(Wn2, Wn2s, 512, 128);

    // CSR build
    hist_kernel<<<(N_EDGES + 255) / 256, 256, 0, stream>>>(eidx, deg);
    scan_kernel<<<1, 1024, 0, stream>>>(deg, rowstart, cursor);
    scatter_kernel<<<(N_EDGES + 255) / 256, 256, 0, stream>>>(eidx, cursor, elist);

    edge_mlp_kernel<<<N_EDGES / 128, 512, 0, stream>>>(
        xb, eidx, edge_attr, We1s, be1, We2s, be2, out_edges);
    agg_kernel<<<N_NODES / 4, 256, 0, stream>>>(out_edges, rowstart, elist, aggb);
    node_mlp_kernel<<<(N_NODES + 63) / 64, 256, 0, stream>>>(
        xb, aggb, Wn1s, bn1, Wn2s, bn2, out);
}

// Round 5
// 594.482 us; speedup vs baseline: 1.1616x; 1.0280x over previous
//
#include <hip/hip_runtime.h>
#include <hip/hip_bf16.h>

#define N_NODES 10000
#define N_EDGES 320000
#define D 128
#define H 512

typedef __bf16 bf16x8 __attribute__((ext_vector_type(8)));
typedef float f32x4 __attribute__((ext_vector_type(4)));
typedef unsigned short u16x8 __attribute__((ext_vector_type(8)));

__device__ __forceinline__ unsigned short f2bf(float f) {
    union { float f; unsigned u; } v; v.f = f;
    unsigned r = v.u + 0x7fffu + ((v.u >> 16) & 1u);
    return (unsigned short)(r >> 16);
}

// ---------------- precompute: cast x to bf16 ----------------
__global__ void cast_x_kernel(const float* __restrict__ x, unsigned short* __restrict__ xb) {
    int t = blockIdx.x * 256 + threadIdx.x;        // exactly N_NODES*D/4 threads
    float4 v = reinterpret_cast<const float4*>(x)[t];
    ushort4 o;
    o.x = f2bf(v.x); o.y = f2bf(v.y); o.z = f2bf(v.z); o.w = f2bf(v.w);
    reinterpret_cast<ushort4*>(xb)[t] = o;
}

// ---------------- precompute: swizzle weight [K][N] fp32 -> MFMA-B-frag layout bf16 ----
__global__ void swizzle_w_kernel(const float* __restrict__ W, unsigned short* __restrict__ out,
                                 int K, int Nn) {
    int t = blockIdx.x * 256 + threadIdx.x;
    int total = (K >> 5) * (Nn >> 4) * 64;
    if (t >= total) return;
    int lane = t & 63;
    int tile = t >> 6;
    int ntiles = Nn >> 4;
    int nt = tile % ntiles;
    int kt = tile / ntiles;
    int k0 = kt * 32 + (lane >> 4) * 8;
    int n  = nt * 16 + (lane & 15);
    unsigned short tmp[8];
#pragma unroll
    for (int j = 0; j < 8; ++j) tmp[j] = f2bf(W[(size_t)(k0 + j) * Nn + n]);
    ushort4* dst = reinterpret_cast<ushort4*>(out + (size_t)t * 8);
    dst[0] = *reinterpret_cast<ushort4*>(&tmp[0]);
    dst[1] = *reinterpret_cast<ushort4*>(&tmp[4]);
}

// ---------------- CSR build: histogram -> scan -> scatter ----------------
__global__ void hist_kernel(const int* __restrict__ eidx, int* __restrict__ deg) {
    int e = blockIdx.x * 256 + threadIdx.x;
    if (e < N_EDGES) atomicAdd(&deg[eidx[N_EDGES + e]], 1);
}

__global__ __launch_bounds__(1024) void scan_kernel(const int* __restrict__ deg,
                                                    int* __restrict__ rowstart,
                                                    int* __restrict__ cursor) {
    __shared__ int wsums[16];
    const int t = threadIdx.x;              // 1024 threads, 10 nodes each
    const int lane = t & 63, wv = t >> 6;
    const int base = t * 10;
    int loc[10];
    int s = 0;
#pragma unroll
    for (int i = 0; i < 10; ++i) {
        int v = (base + i < N_NODES) ? deg[base + i] : 0;
        loc[i] = s; s += v;
    }
    const int tot = s;
    int inc = tot;
#pragma unroll
    for (int d = 1; d < 64; d <<= 1) {
        int n = __shfl_up(inc, d, 64);
        if (lane >= d) inc += n;
    }
    if (lane == 63) wsums[wv] = inc;
    __syncthreads();
    if (t == 0) {
        int run = 0;
#pragma unroll
        for (int w = 0; w < 16; ++w) { int v = wsums[w]; wsums[w] = run; run += v; }
    }
    __syncthreads();
    const int off = wsums[wv] + inc - tot;
#pragma unroll
    for (int i = 0; i < 10; ++i) {
        int idx = base + i;
        if (idx < N_NODES) { int v = off + loc[i]; rowstart[idx] = v; cursor[idx] = v; }
    }
    if (t == 1023) rowstart[N_NODES] = off + tot;
}

__global__ void scatter_kernel(const int* __restrict__ eidx, int* __restrict__ cursor,
                               int* __restrict__ elist) {
    int e = blockIdx.x * 256 + threadIdx.x;
    if (e < N_EDGES) {
        int p = atomicAdd(&cursor[eidx[N_EDGES + e]], 1);
        elist[p] = e;
    }
}

// ---------------- aggregation: one wave per node, CSR order, 4-deep unroll ----------------
__global__ __launch_bounds__(256) void agg_kernel(
    const float* __restrict__ out_edges,
    const int* __restrict__ rowstart,
    const int* __restrict__ elist,
    unsigned short* __restrict__ aggb)      // [N_NODES][128] bf16
{
    int node = blockIdx.x * 4 + (threadIdx.x >> 6);
    int lane = threadIdx.x & 63;
    int r0 = rowstart[node], r1 = rowstart[node + 1];
    float sx = 0.f, sy = 0.f;
    int j = r0;
    for (; j + 4 <= r1; j += 4) {
        int ea_ = elist[j], eb_ = elist[j + 1], ec_ = elist[j + 2], ed_ = elist[j + 3];
        float2 va = *reinterpret_cast<const float2*>(&out_edges[(size_t)ea_ * 128 + lane * 2]);
        float2 vb = *reinterpret_cast<const float2*>(&out_edges[(size_t)eb_ * 128 + lane * 2]);
        float2 vc = *reinterpret_cast<const float2*>(&out_edges[(size_t)ec_ * 128 + lane * 2]);
        float2 vd = *reinterpret_cast<const float2*>(&out_edges[(size_t)ed_ * 128 + lane * 2]);
        sx += (va.x + vb.x) + (vc.x + vd.x);
        sy += (va.y + vb.y) + (vc.y + vd.y);
    }
    for (; j < r1; ++j) {
        int e = elist[j];
        float2 v = *reinterpret_cast<const float2*>(&out_edges[(size_t)e * 128 + lane * 2]);
        sx += v.x; sy += v.y;
    }
    ushort2 o; o.x = f2bf(sx); o.y = f2bf(sy);
    *reinterpret_cast<ushort2*>(&aggb[(size_t)node * 128 + lane * 2]) = o;
}

// ---------------- edge MLP: M=128, 8 waves, 3-deep counted-vmcnt pipeline ----------------
__device__ __forceinline__ void gld_lds16(const void* g, void* l) {
    __builtin_amdgcn_global_load_lds((const __attribute__((address_space(1))) void*)g,
                                     (__attribute__((address_space(3))) void*)l, 16, 0, 0);
}

// LDS layout (shorts): A0/A1/A2 @ 0/4096/8192 (8 KB each, [128 rows][32 k], quad-swizzled)
//                      B0/B1/B2 @ 12288/28672/45056 (32 KB each, frag-linear)
//                      sH0 @ 0, sH1 @ 17408 (aliased after GEMM1)
#define WAITVML(N) do { asm volatile("s_waitcnt vmcnt(" #N ") lgkmcnt(0)" ::: "memory"); \
                        __builtin_amdgcn_sched_barrier(0); } while (0)
#define RBAR()     do { __builtin_amdgcn_s_barrier(); \
                        __builtin_amdgcn_sched_barrier(0); } while (0)

__global__ __launch_bounds__(512, 2) void edge_mlp_kernel(
    const unsigned short* __restrict__ xb,
    const int* __restrict__ eidx,
    const float* __restrict__ edge_attr,
    const unsigned short* __restrict__ We1s,
    const float* __restrict__ be1,
    const unsigned short* __restrict__ We2s,
    const float* __restrict__ be2,
    float* __restrict__ out_edges)
{
    __shared__ unsigned short smem[61440];       // 122880 B
    unsigned short* const sH0 = smem;
    unsigned short* const sH1 = smem + 17408;

    const int tid = threadIdx.x;
    const int wave = tid >> 6, lane = tid & 63;
    const int wr = wave >> 2, wc = wave & 3;     // wave-row (M), wave-col (N)
    const int l15 = lane & 15;
    const int Q = lane >> 4;                     // k-quad 0..3
    const int e0 = blockIdx.x * 128;

    // staging geometry: this lane stages row rs, swizzled source quad sq
    const int rs = wave * 16 + (lane >> 2);
    const int sq = (lane & 3) ^ (rs & 3);
    const int nS = eidx[e0 + rs];
    const int nR = eidx[N_EDGES + e0 + rs];
    const unsigned short* aS = xb + (size_t)nS * 128 + sq * 8;
    const unsigned short* aR = xb + (size_t)nR * 128 + sq * 8;

    // prologue: preload edge_attr (slots 8..11) into regs, convert to bf16
    u16x8 eaw[4];
    {
        const float* aE = edge_attr + (size_t)(e0 + rs) * 128 + sq * 8;
#pragma unroll
        for (int s = 0; s < 4; ++s) {
            float4 v0 = *reinterpret_cast<const float4*>(aE + s * 32);
            float4 v1 = *reinterpret_cast<const float4*>(aE + s * 32 + 4);
            eaw[s][0] = f2bf(v0.x); eaw[s][1] = f2bf(v0.y);
            eaw[s][2] = f2bf(v0.z); eaw[s][3] = f2bf(v0.w);
            eaw[s][4] = f2bf(v1.x); eaw[s][5] = f2bf(v1.y);
            eaw[s][6] = f2bf(v1.z); eaw[s][7] = f2bf(v1.w);
        }
    }

    f32x4 acc1[8][4];
#pragma unroll
    for (int j = 0; j < 8; ++j)
#pragma unroll
        for (int mt = 0; mt < 4; ++mt) acc1[j][mt] = (f32x4){0.f, 0.f, 0.f, 0.f};

#define STAGE(S) do {                                                                   \
        if ((S) < 8) {                                                                  \
            const unsigned short* asrc =                                                \
                ((S) < 4) ? (aS + (S) * 32) : (aR + ((S) - 4) * 32);                    \
            gld_lds16(asrc, smem + ((S) % 3) * 4096 + wave * 512);                      \
        } else {                                                                        \
            *reinterpret_cast<u16x8*>(&smem[((S) % 3) * 4096 + rs * 32 + (lane & 3) * 8]) \
                = eaw[(S) - 8];                                                         \
        }                                                                               \
        _Pragma("unroll")                                                               \
        for (int i = 0; i < 4; ++i)                                                     \
            gld_lds16(We1s + (size_t)(S) * 16384 + (size_t)(wave * 4 + i) * 512 + lane * 8, \
                      smem + 12288 + ((S) % 3) * 16384 + (wave * 4 + i) * 512);         \
    } while (0)

#define MF(KT) do {                                                                     \
        unsigned short* const Ac = smem + ((KT) % 3) * 4096;                            \
        unsigned short* const Bc = smem + 12288 + ((KT) % 3) * 16384;                   \
        bf16x8 a[4];                                                                    \
        _Pragma("unroll")                                                               \
        for (int mt = 0; mt < 4; ++mt) {                                                \
            int R = wr * 64 + mt * 16 + l15;                                            \
            a[mt] = *reinterpret_cast<const bf16x8*>(&Ac[R * 32 + ((Q ^ (R & 3)) * 8)]); \
        }                                                                               \
        _Pragma("unroll")                                                               \
        for (int j = 0; j < 8; ++j) {                                                   \
            int ntile = (j >> 1) * 8 + wc * 2 + (j & 1);                                \
            bf16x8 b = *reinterpret_cast<const bf16x8*>(&Bc[ntile * 512 + lane * 8]);   \
            _Pragma("unroll")                                                           \
            for (int mt = 0; mt < 4; ++mt)                                              \
                acc1[j][mt] = __builtin_amdgcn_mfma_f32_16x16x32_bf16(a[mt], b, acc1[j][mt], 0, 0, 0); \
        }                                                                               \
    } while (0)

    // prologue stage, then 12 pipelined iterations (loads never drained to 0 mid-loop)
    STAGE(0); STAGE(1);
    WAITVML(5); RBAR(); STAGE(2);  MF(0);
    WAITVML(5); RBAR(); STAGE(3);  MF(1);
    WAITVML(5); RBAR(); STAGE(4);  MF(2);
    WAITVML(5); RBAR(); STAGE(5);  MF(3);
    WAITVML(5); RBAR(); STAGE(6);  MF(4);
    WAITVML(5); RBAR(); STAGE(7);  MF(5);
    WAITVML(5); RBAR(); STAGE(8);  MF(6);
    WAITVML(4); RBAR(); STAGE(9);  MF(7);
    WAITVML(4); RBAR(); STAGE(10); MF(8);
    WAITVML(4); RBAR(); STAGE(11); MF(9);
    WAITVML(4); RBAR();            MF(10);
    WAITVML(0); RBAR();            MF(11);

    f32x4 acc2[2][4];
#pragma unroll
    for (int nn = 0; nn < 2; ++nn)
#pragma unroll
        for (int mt = 0; mt < 4; ++mt) acc2[nn][mt] = (f32x4){0.f, 0.f, 0.f, 0.f};

    // ---- hidden chunks -> GEMM2 (sH ping-pong aliased over A/B buffers) ----
#define EWRITE_H(hh, dst)                                                     \
    {                                                                         \
        _Pragma("unroll")                                                     \
        for (int nn = 0; nn < 2; ++nn) {                                      \
            int cc = (wc * 2 + nn) * 16 + l15;                                \
            float bias = be1[(hh) * 128 + cc];                                \
            _Pragma("unroll")                                                 \
            for (int mt = 0; mt < 4; ++mt)                                    \
                _Pragma("unroll")                                             \
                for (int r = 0; r < 4; ++r) {                                 \
                    float v = acc1[(hh) * 2 + nn][mt][r] + bias;              \
                    v = v > 0.f ? v : 0.f;                                    \
                    int row = wr * 64 + mt * 16 + (lane >> 4) * 4 + r;        \
                    (dst)[row * 136 + cc] = f2bf(v);                          \
                }                                                             \
        }                                                                     \
    }

    __syncthreads();                       // all waves done with A/B buffers
    EWRITE_H(0, sH0);
    __syncthreads();
#pragma unroll
    for (int h = 0; h < 4; ++h) {
        unsigned short* const cur = (h & 1) ? sH1 : sH0;
        unsigned short* const nxt = (h & 1) ? sH0 : sH1;
        if (h < 3) EWRITE_H(h + 1, nxt);
#pragma unroll
        for (int kt = 0; kt < 4; ++kt) {
            bf16x8 a[4];
#pragma unroll
            for (int mt = 0; mt < 4; ++mt) {
                int R = wr * 64 + mt * 16 + l15;
                a[mt] = *reinterpret_cast<const bf16x8*>(&cur[R * 136 + kt * 32 + Q * 8]);
            }
#pragma unroll
            for (int nn = 0; nn < 2; ++nn) {
                int ntile = wc * 2 + nn;
                bf16x8 b = *reinterpret_cast<const bf16x8*>(
                    &We2s[(((size_t)(h * 4 + kt) * 8 + ntile) * 64 + lane) * 8]);
#pragma unroll
                for (int mt = 0; mt < 4; ++mt)
                    acc2[nn][mt] = __builtin_amdgcn_mfma_f32_16x16x32_bf16(a[mt], b, acc2[nn][mt], 0, 0, 0);
            }
        }
        if (h < 3) __syncthreads();
    }

    // ---- epilogue: plain stores (L3-resident for agg) ----
#pragma unroll
    for (int nn = 0; nn < 2; ++nn) {
        int cc = (wc * 2 + nn) * 16 + l15;
        float bias = be2[cc];
#pragma unroll
        for (int mt = 0; mt < 4; ++mt)
#pragma unroll
            for (int r = 0; r < 4; ++r) {
                int row = wr * 64 + mt * 16 + (lane >> 4) * 4 + r;
                out_edges[(size_t)(e0 + row) * 128 + cc] = acc2[nn][mt][r] + bias;
            }
    }
}

// ---------------- fused node MLP (unchanged r3 structure) ----------------
#define WRITE_H(hh, dst, B1)                                                  \
    {                                                                         \
        _Pragma("unroll")                                                     \
        for (int nn = 0; nn < 2; ++nn) {                                      \
            int cc = (wave * 2 + nn) * 16 + l15;                              \
            float bias = (B1)[(hh) * 128 + cc];                               \
            _Pragma("unroll")                                                 \
            for (int mt = 0; mt < 4; ++mt)                                    \
                _Pragma("unroll")                                             \
                for (int r = 0; r < 4; ++r) {                                 \
                    float v = acc1[(hh) * 2 + nn][mt][r] + bias;              \
                    v = v > 0.f ? v : 0.f;                                    \
                    int row = mt * 16 + (lane >> 4) * 4 + r;                  \
                    (dst)[row * 136 + cc] = f2bf(v);                          \
                }                                                             \
        }                                                                     \
    }

#define GEMM2_CHUNK(hh, src, W2)                                              \
    {                                                                         \
        _Pragma("unroll")                                                     \
        for (int kt = 0; kt < 4; ++kt) {                                      \
            bf16x8 a[4];                                                      \
            _Pragma("unroll")                                                 \
            for (int mt = 0; mt < 4; ++mt)                                    \
                a[mt] = *reinterpret_cast<const bf16x8*>(                     \
                    &(src)[(mt * 16 + l15) * 136 + kt * 32 + q8]);            \
            _Pragma("unroll")                                                 \
            for (int nn = 0; nn < 2; ++nn) {                                  \
                int ntile = wave * 2 + nn;                                    \
                bf16x8 b = *reinterpret_cast<const bf16x8*>(                  \
                    &(W2)[(((size_t)((hh) * 4 + kt) * 8 + ntile) * 64 + lane) * 8]); \
                _Pragma("unroll")                                             \
                for (int mt = 0; mt < 4; ++mt)                                \
                    acc2[nn][mt] = __builtin_amdgcn_mfma_f32_16x16x32_bf16(   \
                        a[mt], b, acc2[nn][mt], 0, 0, 0);                     \
            }                                                                 \
        }                                                                     \
    }

__global__ __launch_bounds__(256, 2) void node_mlp_kernel(
    const unsigned short* __restrict__ xb,
    const unsigned short* __restrict__ aggb,
    const unsigned short* __restrict__ Wn1s,
    const float* __restrict__ bn1,
    const unsigned short* __restrict__ Wn2s,
    const float* __restrict__ bn2,
    float* __restrict__ out_nodes)
{
    __shared__ unsigned short sA[17408];      // stage [64][264]; sH ping-pong aliased
    unsigned short* const sH0 = sA;
    unsigned short* const sH1 = sA + 64 * 136;

    const int tid = threadIdx.x;
    const int wave = tid >> 6, lane = tid & 63;
    const int n0 = blockIdx.x * 64;
    const int l15 = lane & 15;
    const int q8 = (lane >> 4) * 8;

    for (int c = tid; c < 1024; c += 256) {
        int row = c >> 4;
        int off = (c & 15) << 3;
        int node = n0 + row;
        bf16x8 v = {};
        if (node < N_NODES)
            v = *reinterpret_cast<const bf16x8*>(&xb[(size_t)node * 128 + off]);
        *reinterpret_cast<bf16x8*>(&sA[row * 264 + off]) = v;
    }
    for (int c = tid; c < 1024; c += 256) {
        int row = c >> 4;
        int off = (c & 15) << 3;
        int node = n0 + row;
        bf16x8 v = {};
        if (node < N_NODES)
            v = *reinterpret_cast<const bf16x8*>(&aggb[(size_t)node * 128 + off]);
        *reinterpret_cast<bf16x8*>(&sA[row * 264 + 128 + off]) = v;
    }
    __syncthreads();

    f32x4 acc1[8][4];
#pragma unroll
    for (int j = 0; j < 8; ++j)
#pragma unroll
        for (int mt = 0; mt < 4; ++mt) acc1[j][mt] = (f32x4){0.f, 0.f, 0.f, 0.f};
    f32x4 acc2[2][4];
#pragma unroll
    for (int nn = 0; nn < 2; ++nn)
#pragma unroll
        for (int mt = 0; mt < 4; ++mt) acc2[nn][mt] = (f32x4){0.f, 0.f, 0.f, 0.f};

#pragma unroll 2
    for (int kt = 0; kt < 8; ++kt) {
        bf16x8 a[4];
#pragma unroll
        for (int mt = 0; mt < 4; ++mt)
            a[mt] = *reinterpret_cast<const bf16x8*>(&sA[(mt * 16 + l15) * 264 + kt * 32 + q8]);
#pragma unroll
        for (int j = 0; j < 8; ++j) {
            int ntile = (j >> 1) * 8 + wave * 2 + (j & 1);
            bf16x8 b = *reinterpret_cast<const bf16x8*>(
                &Wn1s[(((size_t)kt * 32 + ntile) * 64 + lane) * 8]);
#pragma unroll
            for (int mt = 0; mt < 4; ++mt)
                acc1[j][mt] = __builtin_amdgcn_mfma_f32_16x16x32_bf16(a[mt], b, acc1[j][mt], 0, 0, 0);
        }
    }

    __syncthreads();
    WRITE_H(0, sH0, bn1);
    __syncthreads();
#pragma unroll
    for (int h = 0; h < 4; ++h) {
        unsigned short* const cur = (h & 1) ? sH1 : sH0;
        unsigned short* const nxt = (h & 1) ? sH0 : sH1;
        if (h < 3) WRITE_H(h + 1, nxt, bn1);
        GEMM2_CHUNK(h, cur, Wn2s);
        if (h < 3) __syncthreads();
    }

#pragma unroll
    for (int nn = 0; nn < 2; ++nn) {
        int cc = (wave * 2 + nn) * 16 + l15;
        float bias = bn2[cc];
#pragma unroll
        for (int mt = 0; mt < 4; ++mt)
#pragma unroll
            for (int r = 0; r < 4; ++r) {
                int row = mt * 16 + (lane >> 4) * 4 + r;
                int node = n0 + row;
                if (node < N_NODES)
                    out_nodes[(size_t)node * 128 + cc] = acc2[nn][mt][r] + bias;
            }
    }
}

extern "C" void kernel_launch(void* const* d_in, const int* in_sizes, int n_in,
                              void* d_out, int out_size, void* d_ws, size_t ws_size,
                              hipStream_t stream) {
    const float* x         = (const float*)d_in[0];
    const int*   eidx      = (const int*)d_in[1];
    const float* edge_attr = (const float*)d_in[2];
    const float* We1       = (const float*)d_in[3];
    const float* be1       = (const float*)d_in[4];
    const float* We2       = (const float*)d_in[5];
    const float* be2       = (const float*)d_in[6];
    const float* Wn1       = (const float*)d_in[7];
    const float* bn1       = (const float*)d_in[8];
    const float* Wn2       = (const float*)d_in[9];
    const float* bn2       = (const float*)d_in[10];
    float* out = (float*)d_out;

    char* ws = (char*)d_ws;
    size_t off = 0;
    auto alloc = [&](size_t bytes) {
        void* p = ws + off;
        off += (bytes + 255) & ~(size_t)255;
        return p;
    };
    unsigned short* xb   = (unsigned short*)alloc((size_t)N_NODES * D * 2);
    unsigned short* We1s = (unsigned short*)alloc((size_t)384 * 512 * 2);
    unsigned short* We2s = (unsigned short*)alloc((size_t)512 * 128 * 2);
    unsigned short* Wn1s = (unsigned short*)alloc((size_t)256 * 512 * 2);
    unsigned short* Wn2s = (unsigned short*)alloc((size_t)512 * 128 * 2);
    unsigned short* aggb = (unsigned short*)alloc((size_t)N_NODES * D * 2);
    int* deg      = (int*)alloc((size_t)(N_NODES + 1) * 4);
    int* rowstart = (int*)alloc((size_t)(N_NODES + 1) * 4);
    int* cursor   = (int*)alloc((size_t)(N_NODES + 1) * 4);
    int* elist    = (int*)alloc((size_t)N_EDGES * 4);

    float* out_edges = out + (size_t)N_NODES * D;

    hipMemsetAsync(deg, 0, (size_t)N_NODES * sizeof(int), stream);
    cast_x_kernel<<<(N_NODES * D / 4 + 255) / 256, 256, 0, stream>>>(x, xb);
    swizzle_w_kernel<<<(12 * 32 * 64 + 255) / 256, 256, 0, stream>>>(We1, We1s, 384, 512);
    swizzle_w_kernel<<<(16 * 8 * 64 + 255) / 256, 256, 0, stream>>>(We2, We2s, 512, 128);
    swizzle_w_kernel<<<(8 * 32 * 64 + 255) / 256, 256, 0, stream>>>(Wn1, Wn1s, 256, 512);
    swizzle_w_kernel<<<(16 * 8 * 64 + 255) / 256, 256, 0, stream>>>(Wn2, Wn2s, 512, 128);

    // CSR build
    hist_kernel<<<(N_EDGES + 255) / 256, 256, 0, stream>>>(eidx, deg);
    scan_kernel<<<1, 1024, 0, stream>>>(deg, rowstart, cursor);
    scatter_kernel<<<(N_EDGES + 255) / 256, 256, 0, stream>>>(eidx, cursor, elist);

    edge_mlp_kernel<<<N_EDGES / 128, 512, 0, stream>>>(
        xb, eidx, edge_attr, We1s, be1, We2s, be2, out_edges);
    agg_kernel<<<N_NODES / 4, 256, 0, stream>>>(out_edges, rowstart, elist, aggb);
    node_mlp_kernel<<<(N_NODES + 63) / 64, 256, 0, stream>>>(
        xb, aggb, Wn1s, bn1, Wn2s, bn2, out);
}